// Round 1
// baseline (166.043 us; speedup 1.0000x reference)
//
#include <hip/hip_runtime.h>
#include <hip/hip_bf16.h>
#include <math.h>

#define DEVI static __device__ __forceinline__

using f32x4  = __attribute__((ext_vector_type(4))) float;
using f32x16 = __attribute__((ext_vector_type(16))) float;
using s16x8  = __attribute__((ext_vector_type(8))) short;
using bf16x8 = __attribute__((ext_vector_type(8))) __bf16;
using i32x4  = __attribute__((ext_vector_type(4))) int;
using u32x2  = __attribute__((ext_vector_type(2))) unsigned int;

constexpr int N   = 8192;
constexpr int KIN = 512;
constexpr int F   = 256;

DEVI unsigned short f2bf(float f) {
  unsigned u = __builtin_bit_cast(unsigned, f);
  return (unsigned short)((u + 0x7FFFu + ((u >> 16) & 1u)) >> 16);
}

DEVI f32x16 mfma32(s16x8 a, s16x8 b, f32x16 c) {
  return __builtin_amdgcn_mfma_f32_32x32x16_bf16(
      __builtin_bit_cast(bf16x8, a), __builtin_bit_cast(bf16x8, b), c, 0, 0, 0);
}

DEVI void gload16(const void* g, void* lds_uniform) {
  __builtin_amdgcn_global_load_lds(
      (const __attribute__((address_space(1))) unsigned*)g,
      (__attribute__((address_space(3))) unsigned*)lds_uniform, 16, 0, 0);
}

// ---------------- cast input f32 -> bf16 (row-major [8192][512]) ----------------
__global__ __launch_bounds__(256) void k_cast(const float* __restrict__ src,
                                              unsigned short* __restrict__ dst,
                                              int n8) {
  int t = blockIdx.x * 256 + threadIdx.x;
  if (t >= n8) return;
  const f32x4* p = (const f32x4*)(src + (size_t)t * 8);
  f32x4 v0 = p[0], v1 = p[1];
  s16x8 o;
  o[0] = (short)f2bf(v0[0]); o[1] = (short)f2bf(v0[1]);
  o[2] = (short)f2bf(v0[2]); o[3] = (short)f2bf(v0[3]);
  o[4] = (short)f2bf(v1[0]); o[5] = (short)f2bf(v1[1]);
  o[6] = (short)f2bf(v1[2]); o[7] = (short)f2bf(v1[3]);
  *(s16x8*)(dst + (size_t)t * 8) = o;
}

// ---------------- W [512][256] f32 -> Wt [256][512] bf16 (transposed) -----------
__global__ __launch_bounds__(256) void k_prep_w(const float* __restrict__ W,
                                                unsigned short* __restrict__ Wt) {
  int t = blockIdx.x * 256 + threadIdx.x;   // 16384 threads
  int c = t >> 6, k0 = (t & 63) * 8;
  s16x8 o;
#pragma unroll
  for (int i = 0; i < 8; ++i) o[i] = (short)f2bf(W[(size_t)(k0 + i) * F + c]);
  *(s16x8*)(Wt + (size_t)c * KIN + k0) = o;
}

// ---------------- h = Xbf @ Wt^T : writes Ht[256][8192] bf16 + E/E5/F/F5 --------
// grid 256 blocks (32 rows each), 512 threads (8 waves, wave = 32x32 tile).
__global__ __launch_bounds__(512) void k_gemm1(const unsigned short* __restrict__ inpb,
                                               const unsigned short* __restrict__ Wt,
                                               const float* __restrict__ a_vec,
                                               unsigned short* __restrict__ Ht,
                                               float* __restrict__ E, float* __restrict__ E5,
                                               float* __restrict__ Fv, float* __restrict__ F5v) {
  __shared__ __align__(16) char lds[4096 + 32768 + 2048];
  char* ldsA = lds;                 // [32 rows][128 B]  (XOR-swizzled)
  char* ldsW = lds + 4096;          // [256 cols][128 B] (XOR-swizzled)
  float* red = (float*)(lds + 36864); // [2][32][8]
  int tid = threadIdx.x, w = tid >> 6, l = tid & 63;
  int r0 = blockIdx.x * 32;
  f32x16 acc;
#pragma unroll
  for (int i = 0; i < 16; ++i) acc[i] = 0.f;

  int lrow8 = l >> 3;
  int koffB = ((l & 7) ^ lrow8) * 8;   // pre-swizzled source k-offset (elements)
  int ra = l & 31, kb = (l >> 5) * 8;
  int colw = w * 32 + ra;

  for (int it = 0; it < 8; ++it) {
    int k0 = it * 64;
    __syncthreads();
    if (w < 4) {
      int row = 8 * w + lrow8;
      gload16(inpb + (size_t)(r0 + row) * KIN + k0 + koffB, ldsA + w * 1024);
    }
#pragma unroll
    for (int qi = 0; qi < 4; ++qi) {
      int q = 4 * w + qi;
      int c = 8 * q + lrow8;
      gload16(Wt + (size_t)c * KIN + k0 + koffB, ldsW + q * 1024);
    }
    __syncthreads();
    s16x8 av[4], bv[4];
#pragma unroll
    for (int kf = 0; kf < 4; ++kf) {
      int kk2 = (kf * 16 + kb) * 2;
      av[kf] = *(const s16x8*)(ldsA + ra * 128 + (kk2 ^ ((ra & 7) << 4)));
      bv[kf] = *(const s16x8*)(ldsW + colw * 128 + (kk2 ^ ((colw & 7) << 4)));
    }
#pragma unroll
    for (int kf = 0; kf < 4; ++kf) acc = mfma32(av[kf], bv[kf], acc);
  }

  // epilogue: store Ht (transposed, bf16) + self/neigh dots from f32 acc
  float a1 = a_vec[colw], a2 = a_vec[256 + colw];
  int rquad = (l >> 5) * 4;
#pragma unroll
  for (int g = 0; g < 4; ++g) {
    int rowb = g * 8 + rquad;
    unsigned short h0 = f2bf(acc[g * 4 + 0]), h1 = f2bf(acc[g * 4 + 1]);
    unsigned short h2 = f2bf(acc[g * 4 + 2]), h3 = f2bf(acc[g * 4 + 3]);
    u32x2 pk;
    pk[0] = (unsigned)h0 | ((unsigned)h1 << 16);
    pk[1] = (unsigned)h2 | ((unsigned)h3 << 16);
    *(u32x2*)(Ht + (size_t)colw * N + r0 + rowb) = pk;
  }
#pragma unroll
  for (int g = 0; g < 16; ++g) {
    float vs = acc[g] * a1;
    float vn = acc[g] * a2;
#pragma unroll
    for (int m = 1; m <= 16; m <<= 1) {
      vs += __shfl_xor(vs, m, 64);
      vn += __shfl_xor(vn, m, 64);
    }
    if ((l & 31) == 0) {
      int row = (g & 3) + 8 * (g >> 2) + rquad;
      red[row * 8 + w] = vs;
      red[256 + row * 8 + w] = vn;
    }
  }
  __syncthreads();
  if (tid < 32) {
    float s = 0.f, n2 = 0.f;
#pragma unroll
    for (int i = 0; i < 8; ++i) { s += red[tid * 8 + i]; n2 += red[256 + tid * 8 + i]; }
    E[r0 + tid]   = expf(s);
    E5[r0 + tid]  = expf(0.2f * s);
    Fv[r0 + tid]  = expf(n2);
    F5v[r0 + tid] = expf(0.2f * n2);
  }
}

// ---------------- fused masked-softmax-numerator @ h (flash-style) --------------
// grid 256 = 128 row-blocks (64 rows) x KSPLIT=2 (j halves). 512 threads, 8 waves,
// wave tile 32x64. Writes partial acc [ks][8192][256] f32 + partial rowsum.
__global__ __launch_bounds__(512) void k_phase2(const int* __restrict__ adj,
                                                const unsigned short* __restrict__ Ht,
                                                const float* __restrict__ E,
                                                const float* __restrict__ E5,
                                                const float* __restrict__ Fv,
                                                const float* __restrict__ F5v,
                                                float* __restrict__ pacc,
                                                float* __restrict__ ps) {
  __shared__ __align__(16) char lds[32768 + 8192 + 2048];
  char* ldsH = lds;            // Ht tile [256 cols][64 k] bf16, swizzled
  char* ldsP = lds + 32768;    // P tile  [64 rows][64 k] bf16, swizzled
  float* ldsS = (float*)(lds + 40960); // [64][8]

  int tid = threadIdx.x, w = tid >> 6, l = tid & 63;
  int bid = blockIdx.x;
  int rb = bid >> 1, ks = bid & 1;
  int r0 = rb * 64;
  int jbase0 = ks * 4096;

  int r = tid >> 3;       // 0..63: P-gen row
  int cch = tid & 7;      // 8-int chunk within 64
  float Er = E[r0 + r], E5r = E5[r0 + r];
  float s_part = 0.f;

  int lrow8 = l >> 3;
  int koffB = ((l & 7) ^ lrow8) * 8;
  int rg = w >> 2, cg = w & 3;
  int pw_byte = r * 128 + ((cch * 16) ^ ((r & 7) << 4));

  f32x16 acc0, acc1;
#pragma unroll
  for (int i = 0; i < 16; ++i) { acc0[i] = 0.f; acc1[i] = 0.f; }

  int ra = rg * 32 + (l & 31);
  int kb = (l >> 5) * 8;
  int col0 = cg * 64 + (l & 31);
  int col1 = col0 + 32;

  for (int it = 0; it < 64; ++it) {
    int j0 = jbase0 + it * 64;
    __syncthreads();
    // stage H tile (global_load_lds, source pre-swizzled, LDS linear)
#pragma unroll
    for (int qi = 0; qi < 4; ++qi) {
      int q = 4 * w + qi;
      int c = 8 * q + lrow8;
      gload16(Ht + (size_t)c * N + j0 + koffB, ldsH + q * 1024);
    }
    // generate P tile
    {
      const int* ap = adj + (size_t)(r0 + r) * N + j0 + cch * 8;
      i32x4 ad0 = *(const i32x4*)ap;
      i32x4 ad1 = *(const i32x4*)(ap + 4);
      f32x4 f0 = *(const f32x4*)(Fv + j0 + cch * 8);
      f32x4 f1 = *(const f32x4*)(Fv + j0 + cch * 8 + 4);
      f32x4 g0 = *(const f32x4*)(F5v + j0 + cch * 8);
      f32x4 g1 = *(const f32x4*)(F5v + j0 + cch * 8 + 4);
      s16x8 pv;
      float ss = 0.f;
#pragma unroll
      for (int i = 0; i < 4; ++i) {
        float t1 = Er * f0[i], t2 = E5r * g0[i];
        float p = (ad0[i] != 0) ? ((t1 >= 1.f) ? t1 : t2) : 0.f;
        ss += p;
        pv[i] = (short)f2bf(p);
      }
#pragma unroll
      for (int i = 0; i < 4; ++i) {
        float t1 = Er * f1[i], t2 = E5r * g1[i];
        float p = (ad1[i] != 0) ? ((t1 >= 1.f) ? t1 : t2) : 0.f;
        ss += p;
        pv[4 + i] = (short)f2bf(p);
      }
      s_part += ss;
      *(s16x8*)(ldsP + pw_byte) = pv;
    }
    __syncthreads();
    // MFMA: wave tile 32 rows x 64 cols, K=64
    s16x8 av[4], bv0[4], bv1[4];
#pragma unroll
    for (int kf = 0; kf < 4; ++kf) {
      int kk2 = (kf * 16 + kb) * 2;
      av[kf]  = *(const s16x8*)(ldsP + ra * 128 + (kk2 ^ ((ra & 7) << 4)));
      bv0[kf] = *(const s16x8*)(ldsH + col0 * 128 + (kk2 ^ ((col0 & 7) << 4)));
      bv1[kf] = *(const s16x8*)(ldsH + col1 * 128 + (kk2 ^ ((col1 & 7) << 4)));
    }
#pragma unroll
    for (int kf = 0; kf < 4; ++kf) {
      acc0 = mfma32(av[kf], bv0[kf], acc0);
      acc1 = mfma32(av[kf], bv1[kf], acc1);
    }
  }

  // epilogue: partial rowsum + partial acc
  ldsS[r * 8 + cch] = s_part;
  __syncthreads();
  if (tid < 64) {
    float s = 0.f;
#pragma unroll
    for (int i = 0; i < 8; ++i) s += ldsS[tid * 8 + i];
    ps[ks * N + r0 + tid] = s;
  }
  float* po = pacc + (size_t)ks * N * F;
#pragma unroll
  for (int g = 0; g < 16; ++g) {
    int row = rg * 32 + (g & 3) + 8 * (g >> 2) + (l >> 5) * 4;
    po[(size_t)(r0 + row) * F + col0] = acc0[g];
    po[(size_t)(r0 + row) * F + col1] = acc1[g];
  }
}

// ---------------- combine split-K partials, normalize, ELU ----------------------
__global__ __launch_bounds__(256) void k_combine(const float* __restrict__ pacc,
                                                 const float* __restrict__ ps,
                                                 float* __restrict__ out) {
  int t = blockIdx.x * 256 + threadIdx.x;  // 524288 threads
  size_t idx = (size_t)t * 4;
  int row = (int)(idx >> 8);
  f32x4 a0 = *(const f32x4*)(pacc + idx);
  f32x4 a1 = *(const f32x4*)(pacc + (size_t)N * F + idx);
  float inv = 1.f / (ps[row] + ps[N + row]);
  f32x4 o;
#pragma unroll
  for (int i = 0; i < 4; ++i) {
    float v = (a0[i] + a1[i]) * inv;
    o[i] = v > 0.f ? v : expm1f(v);
  }
  *(f32x4*)(out + idx) = o;
}

extern "C" void kernel_launch(void* const* d_in, const int* in_sizes, int n_in,
                              void* d_out, int out_size, void* d_ws, size_t ws_size,
                              hipStream_t stream) {
  const float* input = (const float*)d_in[0];
  const int*   adj   = (const int*)d_in[1];
  const float* W     = (const float*)d_in[2];
  const float* a     = (const float*)d_in[3];
  float* out = (float*)d_out;
  char* ws = (char*)d_ws;

  unsigned short* inpb = (unsigned short*)(ws);              // 8,388,608 B
  unsigned short* Wt   = (unsigned short*)(ws + 8388608);    //   262,144 B
  unsigned short* Ht   = (unsigned short*)(ws + 8650752);    // 4,194,304 B
  float* E    = (float*)(ws + 12845056);                     //    32,768 B
  float* E5   = (float*)(ws + 12877824);
  float* Fv   = (float*)(ws + 12910592);
  float* F5   = (float*)(ws + 12943360);
  float* ps   = (float*)(ws + 12976128);                     //    65,536 B
  float* pacc = (float*)(ws + 13041664);                     // 16,777,216 B

  hipLaunchKernelGGL(k_cast,   dim3(2048), dim3(256), 0, stream, input, inpb, 524288);
  hipLaunchKernelGGL(k_prep_w, dim3(64),   dim3(256), 0, stream, W, Wt);
  hipLaunchKernelGGL(k_gemm1,  dim3(256),  dim3(512), 0, stream, inpb, Wt, a, Ht, E, E5, Fv, F5);
  hipLaunchKernelGGL(k_phase2, dim3(256),  dim3(512), 0, stream, adj, Ht, E, E5, Fv, F5, pacc, ps);
  hipLaunchKernelGGL(k_combine,dim3(2048), dim3(256), 0, stream, pacc, ps, out);
}

// Round 2
// 135.409 us; speedup vs baseline: 1.2262x; 1.2262x over previous
//
#include <hip/hip_runtime.h>
#include <hip/hip_bf16.h>
#include <math.h>

#define DEVI static __device__ __forceinline__

using f32x4  = __attribute__((ext_vector_type(4))) float;
using f32x16 = __attribute__((ext_vector_type(16))) float;
using s16x8  = __attribute__((ext_vector_type(8))) short;
using bf16x8 = __attribute__((ext_vector_type(8))) __bf16;
using i32x4  = __attribute__((ext_vector_type(4))) int;
using u32x2  = __attribute__((ext_vector_type(2))) unsigned int;

constexpr int N   = 8192;
constexpr int KIN = 512;
constexpr int F   = 256;

DEVI unsigned short f2bf(float f) {
  unsigned u = __builtin_bit_cast(unsigned, f);
  return (unsigned short)((u + 0x7FFFu + ((u >> 16) & 1u)) >> 16);
}

DEVI f32x16 mfma32(s16x8 a, s16x8 b, f32x16 c) {
  return __builtin_amdgcn_mfma_f32_32x32x16_bf16(
      __builtin_bit_cast(bf16x8, a), __builtin_bit_cast(bf16x8, b), c, 0, 0, 0);
}

DEVI void gload16(const void* g, void* lds_uniform) {
  __builtin_amdgcn_global_load_lds(
      (const __attribute__((address_space(1))) unsigned*)g,
      (__attribute__((address_space(3))) unsigned*)lds_uniform, 16, 0, 0);
}

// ---------------- cast input f32 -> bf16 (row-major [8192][512]) ----------------
__global__ __launch_bounds__(256) void k_cast(const float* __restrict__ src,
                                              unsigned short* __restrict__ dst,
                                              int n8) {
  int t = blockIdx.x * 256 + threadIdx.x;
  if (t >= n8) return;
  const f32x4* p = (const f32x4*)(src + (size_t)t * 8);
  f32x4 v0 = p[0], v1 = p[1];
  s16x8 o;
  o[0] = (short)f2bf(v0[0]); o[1] = (short)f2bf(v0[1]);
  o[2] = (short)f2bf(v0[2]); o[3] = (short)f2bf(v0[3]);
  o[4] = (short)f2bf(v1[0]); o[5] = (short)f2bf(v1[1]);
  o[6] = (short)f2bf(v1[2]); o[7] = (short)f2bf(v1[3]);
  *(s16x8*)(dst + (size_t)t * 8) = o;
}

// ---------------- W [512][256] f32 -> Wt [256][512] bf16 (transposed) -----------
__global__ __launch_bounds__(256) void k_prep_w(const float* __restrict__ W,
                                                unsigned short* __restrict__ Wt) {
  int t = blockIdx.x * 256 + threadIdx.x;   // 16384 threads
  int c = t >> 6, k0 = (t & 63) * 8;
  s16x8 o;
#pragma unroll
  for (int i = 0; i < 8; ++i) o[i] = (short)f2bf(W[(size_t)(k0 + i) * F + c]);
  *(s16x8*)(Wt + (size_t)c * KIN + k0) = o;
}

// ---------------- h = Xbf @ Wt^T : writes Ht[256][8192] bf16 + E/E5/F/F5 --------
__global__ __launch_bounds__(512) void k_gemm1(const unsigned short* __restrict__ inpb,
                                               const unsigned short* __restrict__ Wt,
                                               const float* __restrict__ a_vec,
                                               unsigned short* __restrict__ Ht,
                                               float* __restrict__ E, float* __restrict__ E5,
                                               float* __restrict__ Fv, float* __restrict__ F5v) {
  __shared__ __align__(16) char lds[4096 + 32768 + 2048];
  char* ldsA = lds;                 // [32 rows][128 B]  (XOR-swizzled)
  char* ldsW = lds + 4096;          // [256 cols][128 B] (XOR-swizzled)
  float* red = (float*)(lds + 36864); // [2][32][8]
  int tid = threadIdx.x, w = tid >> 6, l = tid & 63;
  int r0 = blockIdx.x * 32;
  f32x16 acc;
#pragma unroll
  for (int i = 0; i < 16; ++i) acc[i] = 0.f;

  int lrow8 = l >> 3;
  int koffB = ((l & 7) ^ lrow8) * 8;   // pre-swizzled source k-offset (elements)
  int ra = l & 31, kb = (l >> 5) * 8;
  int colw = w * 32 + ra;

  for (int it = 0; it < 8; ++it) {
    int k0 = it * 64;
    __syncthreads();
    if (w < 4) {
      int row = 8 * w + lrow8;
      gload16(inpb + (size_t)(r0 + row) * KIN + k0 + koffB, ldsA + w * 1024);
    }
#pragma unroll
    for (int qi = 0; qi < 4; ++qi) {
      int q = 4 * w + qi;
      int c = 8 * q + lrow8;
      gload16(Wt + (size_t)c * KIN + k0 + koffB, ldsW + q * 1024);
    }
    __syncthreads();
    s16x8 av[4], bv[4];
#pragma unroll
    for (int kf = 0; kf < 4; ++kf) {
      int kk2 = (kf * 16 + kb) * 2;
      av[kf] = *(const s16x8*)(ldsA + ra * 128 + (kk2 ^ ((ra & 7) << 4)));
      bv[kf] = *(const s16x8*)(ldsW + colw * 128 + (kk2 ^ ((colw & 7) << 4)));
    }
#pragma unroll
    for (int kf = 0; kf < 4; ++kf) acc = mfma32(av[kf], bv[kf], acc);
  }

  float a1 = a_vec[colw], a2 = a_vec[256 + colw];
  int rquad = (l >> 5) * 4;
#pragma unroll
  for (int g = 0; g < 4; ++g) {
    int rowb = g * 8 + rquad;
    unsigned short h0 = f2bf(acc[g * 4 + 0]), h1 = f2bf(acc[g * 4 + 1]);
    unsigned short h2 = f2bf(acc[g * 4 + 2]), h3 = f2bf(acc[g * 4 + 3]);
    u32x2 pk;
    pk[0] = (unsigned)h0 | ((unsigned)h1 << 16);
    pk[1] = (unsigned)h2 | ((unsigned)h3 << 16);
    *(u32x2*)(Ht + (size_t)colw * N + r0 + rowb) = pk;
  }
#pragma unroll
  for (int g = 0; g < 16; ++g) {
    float vs = acc[g] * a1;
    float vn = acc[g] * a2;
#pragma unroll
    for (int m = 1; m <= 16; m <<= 1) {
      vs += __shfl_xor(vs, m, 64);
      vn += __shfl_xor(vn, m, 64);
    }
    if ((l & 31) == 0) {
      int row = (g & 3) + 8 * (g >> 2) + rquad;
      red[row * 8 + w] = vs;
      red[256 + row * 8 + w] = vn;
    }
  }
  __syncthreads();
  if (tid < 32) {
    float s = 0.f, n2 = 0.f;
#pragma unroll
    for (int i = 0; i < 8; ++i) { s += red[tid * 8 + i]; n2 += red[256 + tid * 8 + i]; }
    E[r0 + tid]   = expf(s);
    E5[r0 + tid]  = expf(0.2f * s);
    Fv[r0 + tid]  = expf(n2);
    F5v[r0 + tid] = expf(0.2f * n2);
  }
}

// ---------------- fused masked-softmax-numerator @ h (2-phase pipelined) --------
// grid 256 = 128 row-blocks (64 rows) x KSPLIT=2. 512 threads, 8 waves.
// Double-buffered ldsH/ldsP, reg-prefetched adj/F, counted vmcnt, 1 barrier/iter.
// Per-wave VMEM order per iter: [pf next: 6 loads] ... [stage next: 4 gload_lds].
// At the wait point, outstanding = stage(cur)[4 oldest] + pf(next)[6 newest]
// -> s_waitcnt vmcnt(6) retires exactly stage(cur). Wrap indexing keeps counts
// uniform across all 64 iterations (no tail peel).
__global__ __launch_bounds__(512) void k_phase2(const int* __restrict__ adj,
                                                const unsigned short* __restrict__ Ht,
                                                const float* __restrict__ E,
                                                const float* __restrict__ E5,
                                                const float* __restrict__ Fv,
                                                const float* __restrict__ F5v,
                                                float* __restrict__ pacc,
                                                float* __restrict__ ps) {
  __shared__ __align__(16) char lds[65536 + 16384];
  char* ldsH = lds;            // 2 x [256 cols][64 k] bf16, swizzled
  char* ldsP = lds + 65536;    // 2 x [64 rows][64 k] bf16, swizzled

  int tid = threadIdx.x, w = tid >> 6, l = tid & 63;
  int bid = blockIdx.x;
  int rb = bid >> 1, ks = bid & 1;
  int r0 = rb * 64;
  int jbase0 = ks * 4096;

  int r = tid >> 3;       // 0..63: P-gen row
  int cch = tid & 7;      // 8-int chunk within 64
  float Er = E[r0 + r], E5r = E5[r0 + r];
  float s_part = 0.f;

  int lrow8 = l >> 3;
  int koffB = ((l & 7) ^ lrow8) * 8;
  int rg = w >> 2, cg = w & 3;
  int pw_byte = r * 128 + ((cch * 16) ^ ((r & 7) << 4));

  f32x16 acc0, acc1;
#pragma unroll
  for (int i = 0; i < 16; ++i) { acc0[i] = 0.f; acc1[i] = 0.f; }

  int ra = rg * 32 + (l & 31);
  int kb = (l >> 5) * 8;
  int col0 = cg * 64 + (l & 31);
  int col1 = col0 + 32;

  const size_t adj_row = (size_t)(r0 + r) * N;

  // ---- prologue: prefetch regs for it=0, stage H(0) into buffer 0 ----
  i32x4 ad0 = *(const i32x4*)(adj + adj_row + jbase0 + cch * 8);
  i32x4 ad1 = *(const i32x4*)(adj + adj_row + jbase0 + cch * 8 + 4);
  f32x4 f0 = *(const f32x4*)(Fv + jbase0 + cch * 8);
  f32x4 f1 = *(const f32x4*)(Fv + jbase0 + cch * 8 + 4);
  f32x4 g0 = *(const f32x4*)(F5v + jbase0 + cch * 8);
  f32x4 g1 = *(const f32x4*)(F5v + jbase0 + cch * 8 + 4);
#pragma unroll
  for (int qi = 0; qi < 4; ++qi) {
    int q = 4 * w + qi;
    int c = 8 * q + lrow8;
    gload16(Ht + (size_t)c * N + jbase0 + koffB, ldsH + q * 1024);
  }

  for (int it = 0; it < 64; ++it) {
    int cur = it & 1;
    char* Hc = ldsH + cur * 32768;
    char* Hn = ldsH + (cur ^ 1) * 32768;
    char* Pc = ldsP + cur * 8192;
    int jn = jbase0 + ((it + 1) & 63) * 64;

    // issue next-iteration register prefetch (6 VMEM loads)
    i32x4 nad0 = *(const i32x4*)(adj + adj_row + jn + cch * 8);
    i32x4 nad1 = *(const i32x4*)(adj + adj_row + jn + cch * 8 + 4);
    f32x4 nf0 = *(const f32x4*)(Fv + jn + cch * 8);
    f32x4 nf1 = *(const f32x4*)(Fv + jn + cch * 8 + 4);
    f32x4 ng0 = *(const f32x4*)(F5v + jn + cch * 8);
    f32x4 ng1 = *(const f32x4*)(F5v + jn + cch * 8 + 4);

    // P-gen(it) from current regs, write to ldsP[cur]
    s16x8 pv;
    {
      float ss = 0.f;
#pragma unroll
      for (int i = 0; i < 4; ++i) {
        float t1 = Er * f0[i], t2 = E5r * g0[i];
        float p = (ad0[i] != 0) ? ((t1 >= 1.f) ? t1 : t2) : 0.f;
        ss += p; pv[i] = (short)f2bf(p);
      }
#pragma unroll
      for (int i = 0; i < 4; ++i) {
        float t1 = Er * f1[i], t2 = E5r * g1[i];
        float p = (ad1[i] != 0) ? ((t1 >= 1.f) ? t1 : t2) : 0.f;
        ss += p; pv[4 + i] = (short)f2bf(p);
      }
      s_part += ss;
    }
    *(s16x8*)(Pc + pw_byte) = pv;

    // wait: own P write visible (lgkm) + H(it) staging done (vmcnt(6) leaves
    // only the 6 pf(next) loads in flight), then cross-wave barrier.
    asm volatile("s_waitcnt vmcnt(6) lgkmcnt(0)" ::: "memory");
    __builtin_amdgcn_s_barrier();

    // fragment reads from current buffers
    s16x8 av[4], bv0[4], bv1[4];
#pragma unroll
    for (int kf = 0; kf < 4; ++kf) {
      int kk2 = (kf * 16 + kb) * 2;
      av[kf]  = *(const s16x8*)(Pc + ra * 128 + (kk2 ^ ((ra & 7) << 4)));
      bv0[kf] = *(const s16x8*)(Hc + col0 * 128 + (kk2 ^ ((col0 & 7) << 4)));
      bv1[kf] = *(const s16x8*)(Hc + col1 * 128 + (kk2 ^ ((col1 & 7) << 4)));
    }
    asm volatile("s_waitcnt lgkmcnt(0)" ::: "memory");
    __builtin_amdgcn_sched_barrier(0);

    // issue next H stage into the other buffer (safe: all waves passed the
    // barrier above, so no one still reads Hn's previous contents)
#pragma unroll
    for (int qi = 0; qi < 4; ++qi) {
      int q = 4 * w + qi;
      int c = 8 * q + lrow8;
      gload16(Ht + (size_t)c * N + jn + koffB, Hn + q * 1024);
    }

#pragma unroll
    for (int kf = 0; kf < 4; ++kf) {
      acc0 = mfma32(av[kf], bv0[kf], acc0);
      acc1 = mfma32(av[kf], bv1[kf], acc1);
    }

    ad0 = nad0; ad1 = nad1; f0 = nf0; f1 = nf1; g0 = ng0; g1 = ng1;
  }

  // ---- epilogue ----
  __syncthreads();                       // full drain before LDS reuse
  float* ldsS = (float*)ldsP;            // [64][8]
  ldsS[r * 8 + cch] = s_part;
  __syncthreads();
  if (tid < 64) {
    float s = 0.f;
#pragma unroll
    for (int i = 0; i < 8; ++i) s += ldsS[tid * 8 + i];
    ps[ks * N + r0 + tid] = s;
  }
  float* po = pacc + (size_t)ks * N * F;
#pragma unroll
  for (int g = 0; g < 16; ++g) {
    int row = rg * 32 + (g & 3) + 8 * (g >> 2) + (l >> 5) * 4;
    po[(size_t)(r0 + row) * F + col0] = acc0[g];
    po[(size_t)(r0 + row) * F + col1] = acc1[g];
  }
}

// ---------------- combine split-K partials, normalize, ELU ----------------------
__global__ __launch_bounds__(256) void k_combine(const float* __restrict__ pacc,
                                                 const float* __restrict__ ps,
                                                 float* __restrict__ out) {
  int t = blockIdx.x * 256 + threadIdx.x;  // 524288 threads
  size_t idx = (size_t)t * 4;
  int row = (int)(idx >> 8);
  f32x4 a0 = *(const f32x4*)(pacc + idx);
  f32x4 a1 = *(const f32x4*)(pacc + (size_t)N * F + idx);
  float inv = 1.f / (ps[row] + ps[N + row]);
  f32x4 o;
#pragma unroll
  for (int i = 0; i < 4; ++i) {
    float v = (a0[i] + a1[i]) * inv;
    o[i] = v > 0.f ? v : expm1f(v);
  }
  *(f32x4*)(out + idx) = o;
}

extern "C" void kernel_launch(void* const* d_in, const int* in_sizes, int n_in,
                              void* d_out, int out_size, void* d_ws, size_t ws_size,
                              hipStream_t stream) {
  const float* input = (const float*)d_in[0];
  const int*   adj   = (const int*)d_in[1];
  const float* W     = (const float*)d_in[2];
  const float* a     = (const float*)d_in[3];
  float* out = (float*)d_out;
  char* ws = (char*)d_ws;

  unsigned short* inpb = (unsigned short*)(ws);              // 8,388,608 B
  unsigned short* Wt   = (unsigned short*)(ws + 8388608);    //   262,144 B
  unsigned short* Ht   = (unsigned short*)(ws + 8650752);    // 4,194,304 B
  float* E    = (float*)(ws + 12845056);                     //    32,768 B
  float* E5   = (float*)(ws + 12877824);
  float* Fv   = (float*)(ws + 12910592);
  float* F5   = (float*)(ws + 12943360);
  float* ps   = (float*)(ws + 12976128);                     //    65,536 B
  float* pacc = (float*)(ws + 13041664);                     // 16,777,216 B

  hipLaunchKernelGGL(k_cast,   dim3(2048), dim3(256), 0, stream, input, inpb, 524288);
  hipLaunchKernelGGL(k_prep_w, dim3(64),   dim3(256), 0, stream, W, Wt);
  hipLaunchKernelGGL(k_gemm1,  dim3(256),  dim3(512), 0, stream, inpb, Wt, a, Ht, E, E5, Fv, F5);
  hipLaunchKernelGGL(k_phase2, dim3(256),  dim3(512), 0, stream, adj, Ht, E, E5, Fv, F5, pacc, ps);
  hipLaunchKernelGGL(k_combine,dim3(2048), dim3(256), 0, stream, pacc, ps, out);
}